// Round 10
// baseline (178.639 us; speedup 1.0000x reference)
//
#include <hip/hip_runtime.h>
#include <hip/hip_cooperative_groups.h>
#include <hip/hip_bf16.h>
#include <stdint.h>

namespace cg = cooperative_groups;

#define N_NODES 100000
#define F_IN    512
#define HOUT    16

#define BSH   8                       // 256 nodes per bucket
#define NBUK  391                     // ceil(100000 / 256)
#define CAP   9216                    // per-bucket capacity (mean 8184, +11 sigma)
#define CHUNK 4096                    // edges per binning chunk
#define NTILES 6250                   // GEMM row tiles (16 rows each)
#define GRIDN 256                     // cooperative grid: 1 block/CU

typedef __attribute__((ext_vector_type(8))) short bf16x8;
typedef __attribute__((ext_vector_type(4))) float f32x4;

// f32 -> bf16 bits, round-to-nearest-even
__device__ __forceinline__ short f2bf(float f) {
    union { float f; uint32_t u; } v; v.f = f;
    uint32_t r = (v.u + 0x7FFFu + ((v.u >> 16) & 1u)) >> 16;
    return (short)r;
}
__device__ __forceinline__ float bf2f(uint32_t bits16) {
    union { uint32_t u; float f; } v; v.u = bits16 << 16;
    return v.f;
}

__device__ __forceinline__ int edge_at(const void* ei, int64_t idx, uint32_t is64) {
    if (is64) return (int)((const long long*)ei)[idx];
    return ((const int*)ei)[idx];
}

__global__ __launch_bounds__(1024, 4) void k_mega(
        const void* __restrict__ ei, int E, int nchunks,
        uint32_t* __restrict__ woff, uint32_t* __restrict__ gpairs,
        const float* __restrict__ x, const float* __restrict__ W,
        ushort* __restrict__ hb, uint32_t* __restrict__ cnt,
        const float* __restrict__ bias, float* __restrict__ out) {
    __shared__ __align__(16) uint32_t pool[10240]; // 40 KB phase-union
    __shared__ uint32_t sh_flag;
    const int t = threadIdx.x;

    // per-block edge dtype detect (int64 => odd u32 words all zero)
    if (t == 0) {
        uint32_t o = 0;
        #pragma unroll
        for (int i = 1; i < 32; i += 2) o |= ((const uint32_t*)ei)[i];
        sh_flag = (o == 0u) ? 1u : 0u;
    }
    __syncthreads();
    const uint32_t is64 = sh_flag;
    const bool evenE = ((E & 1) == 0);

    // ======== Phase A1: edge binning (striped chunks) ========
    uint32_t* h      = pool;                    // 512
    uint32_t* ex     = pool + 512;              // 512
    uint32_t* pcnt   = pool + 1024;             // 512
    uint32_t* gbase  = pool + 1536;             // 512
    uint32_t* sorted = pool + 2048;             // 4096 (16 KB)
    uint16_t* sbuck  = (uint16_t*)(pool + 6144);// 4096 u16 (8 KB)

    for (int c = blockIdx.x; c < nchunks; c += GRIDN) {
        if (t < 512) h[t] = 0;
        __syncthreads();
        const int base = c * CHUNK;
        const int chunk_n = min(CHUNK, E - base);

        uint32_t pr[4];
        uint16_t bk[4];
        #pragma unroll
        for (int k = 0; k < 2; ++k) {
            const int e0 = base + k * 2048 + 2 * t;
            uint32_t s0 = 0, s1 = 0, d0 = 0, d1 = 0;
            const bool ok0 = (e0 < E), ok1 = (e0 + 1 < E);
            if (ok1 && evenE) {
                if (is64) {
                    ulonglong2 S = *(const ulonglong2*)((const long long*)ei + e0);
                    ulonglong2 D = *(const ulonglong2*)((const long long*)ei + (int64_t)E + e0);
                    s0 = (uint32_t)S.x; s1 = (uint32_t)S.y;
                    d0 = (uint32_t)D.x; d1 = (uint32_t)D.y;
                } else {
                    uint2 S = *(const uint2*)((const int*)ei + e0);
                    uint2 D = *(const uint2*)((const int*)ei + (int64_t)E + e0);
                    s0 = S.x; s1 = S.y; d0 = D.x; d1 = D.y;
                }
            } else {
                if (ok0) { s0 = (uint32_t)edge_at(ei, e0, is64);
                           d0 = (uint32_t)edge_at(ei, (int64_t)E + e0, is64); }
                if (ok1) { s1 = (uint32_t)edge_at(ei, e0 + 1, is64);
                           d1 = (uint32_t)edge_at(ei, (int64_t)E + e0 + 1, is64); }
            }
            bk[2*k]   = 0xFFFFu;
            bk[2*k+1] = 0xFFFFu;
            if (ok0) {
                uint32_t b = d0 >> BSH;
                pr[2*k] = (s0 << BSH) | (d0 & 255u);
                bk[2*k] = (uint16_t)b;
                atomicAdd(&h[b], 1u);
            }
            if (ok1) {
                uint32_t b = d1 >> BSH;
                pr[2*k+1] = (s1 << BSH) | (d1 & 255u);
                bk[2*k+1] = (uint16_t)b;
                atomicAdd(&h[b], 1u);
            }
        }
        __syncthreads();

        // wave-shfl scan over 512 bins (first 8 waves)
        uint32_t hv = 0, v = 0;
        if (t < 512) {
            hv = h[t]; v = hv;
            #pragma unroll
            for (int d = 1; d < 64; d <<= 1) {
                uint32_t u = __shfl_up(v, d, 64);
                if ((t & 63) >= d) v += u;
            }
            h[t] = v;
        }
        __syncthreads();
        if (t < 512) {
            uint32_t wbase = 0;
            const int w = t >> 6;
            for (int w2 = 0; w2 < w; ++w2) wbase += h[w2 * 64 + 63];
            const uint32_t exv = wbase + v - hv;
            ex[t] = exv;
            pcnt[t] = exv;
            if (t < NBUK) gbase[t] = atomicAdd(&woff[t], hv);
        }
        __syncthreads();

        #pragma unroll
        for (int k = 0; k < 4; ++k) {
            if (bk[k] != 0xFFFFu) {
                uint32_t slot = atomicAdd(&pcnt[bk[k]], 1u);
                sorted[slot] = pr[k];
                sbuck[slot] = bk[k];
            }
        }
        __syncthreads();

        #pragma unroll
        for (int k = 0; k < 4; ++k) {
            int i = k * 1024 + t;
            if (i < chunk_n) {
                uint32_t b = sbuck[i];
                uint32_t pos = gbase[b] + ((uint32_t)i - ex[b]);
                gpairs[(size_t)b * CAP + pos] = sorted[i];
            }
        }
        __syncthreads();
    }

    // ======== Phase A2: GEMM hb = bf16(x @ W) (W staged in LDS) ========
    __syncthreads();
    ushort* wlds = (ushort*)(pool + 2048); // 1024 entries * 16 B = 16 KB
    {
        const int ent = t;
        const int s  = ent >> 6;
        const int hf = (ent >> 4) & 3;
        const int c2 = ent & 15;
        ushort u[8];
        #pragma unroll
        for (int e = 0; e < 8; ++e)
            u[e] = (ushort)f2bf(W[(32 * s + 8 * hf + e) * HOUT + c2]);
        *(ulonglong2*)(wlds + (size_t)ent * 8) = *(const ulonglong2*)u;
    }
    __syncthreads();

    {
        const int lane = t & 63;
        const int wid  = t >> 6;
        const int c2   = lane & 15;
        const int half = lane >> 4;
        const ushort* wb = wlds + (size_t)(half * 16 + c2) * 8;

        for (int tile = blockIdx.x * 16 + wid; tile < NTILES; tile += GRIDN * 16) {
            const int row = tile * 16 + c2;
            const float* xr = x + (int64_t)row * F_IN + half * 8;

            float4 xa[3], xb2[3];
            #pragma unroll
            for (int p = 0; p < 3; ++p) {
                xa[p]  = *(const float4*)(xr + 32 * p);
                xb2[p] = *(const float4*)(xr + 32 * p + 4);
            }
            f32x4 acc = {0.f, 0.f, 0.f, 0.f};
            #pragma unroll
            for (int s = 0; s < 16; ++s) {
                const int p = s % 3;
                bf16x8 bf = *(const bf16x8*)(wb + (size_t)s * 512);
                bf16x8 af;
                af[0] = f2bf(xa[p].x);  af[1] = f2bf(xa[p].y);
                af[2] = f2bf(xa[p].z);  af[3] = f2bf(xa[p].w);
                af[4] = f2bf(xb2[p].x); af[5] = f2bf(xb2[p].y);
                af[6] = f2bf(xb2[p].z); af[7] = f2bf(xb2[p].w);
                if (s + 3 < 16) {
                    xa[p]  = *(const float4*)(xr + 32 * (s + 3));
                    xb2[p] = *(const float4*)(xr + 32 * (s + 3) + 4);
                }
                acc = __builtin_amdgcn_mfma_f32_16x16x32_bf16(af, bf, acc, 0, 0, 0);
            }
            #pragma unroll
            for (int r = 0; r < 4; ++r) {
                int orow = tile * 16 + 4 * half + r;
                hb[(int64_t)orow * HOUT + c2] = (ushort)f2bf(acc[r]);
            }
        }
    }

    cg::this_grid().sync();

    // ======== Phase B: per-bucket histogram -> cnt; hb *= dinv in place ==
    uint32_t* lc = pool;
    for (int b = blockIdx.x; b < NBUK; b += GRIDN) {
        __syncthreads();
        if (t < 256) lc[t] = 0;
        __syncthreads();
        const uint32_t count = woff[b];
        const uint32_t* gp = gpairs + (size_t)b * CAP;
        for (uint32_t i = t; i < count; i += 1024)
            atomicAdd(&lc[gp[i] & 255u], 1u);
        __syncthreads();
        const int gn = (b << BSH) + t;
        if (t < 256 && gn < N_NODES) {
            const uint32_t deg = lc[t];
            cnt[gn] = deg;
            const float dinv = rsqrtf((float)(deg + 1u));
            ushort* row = hb + (size_t)gn * HOUT;
            ulonglong4 rv = *(const ulonglong4*)row;
            ushort u[16];
            *(ulonglong4*)u = rv;
            #pragma unroll
            for (int q = 0; q < 16; ++q)
                u[q] = (ushort)f2bf(bf2f(u[q]) * dinv);
            *(ulonglong4*)row = *(const ulonglong4*)u;
        }
    }

    cg::this_grid().sync();

    // ======== Phase C: per-bucket LDS sort + gather-aggregate + epilogue ==
    uint32_t* st   = pool + 256;
    uint32_t* cur  = pool + 512;
    uint32_t* lsrc = pool + 768; // 9216 u32 = 36 KB
    const uint32_t* hb32 = (const uint32_t*)hb;
    const int f8 = t & 7;
    const int g  = t >> 3;
    const float b0 = bias[2 * f8];
    const float b1 = bias[2 * f8 + 1];

    for (int bk_ = blockIdx.x; bk_ < NBUK; bk_ += GRIDN) {
        __syncthreads();
        if (t < 256) {
            int gn = (bk_ << BSH) + t;
            lc[t] = (gn < N_NODES) ? cnt[gn] : 0u;
        }
        __syncthreads();
        if (t < 256) {
            const uint32_t hv = lc[t];
            uint32_t v = hv;
            #pragma unroll
            for (int d = 1; d < 64; d <<= 1) {
                uint32_t u = __shfl_up(v, d, 64);
                if ((t & 63) >= d) v += u;
            }
            cur[t] = v; // wave-inclusive (temp)
        }
        __syncthreads();
        if (t < 256) {
            uint32_t wb2 = 0;
            const int w = t >> 6;
            for (int w2 = 0; w2 < w; ++w2) wb2 += cur[w2 * 64 + 63];
            st[t] = wb2 + cur[t] - lc[t];
        }
        __syncthreads();
        if (t < 256) cur[t] = st[t];
        __syncthreads();

        const uint32_t count = woff[bk_];
        const uint32_t* gp = gpairs + (size_t)bk_ * CAP;
        for (uint32_t i = t; i < count; i += 1024) {
            uint32_t p = gp[i];
            uint32_t pos = atomicAdd(&cur[p & 255u], 1u);
            lsrc[pos] = p >> BSH;
        }
        __syncthreads();

        #pragma unroll
        for (int i2 = 0; i2 < 2; ++i2) {
            int dl = g + 128 * i2;
            int gn = (bk_ << BSH) + dl;
            if (gn >= N_NODES) break;
            const uint32_t s0 = st[dl];
            const uint32_t n  = lc[dl];

            float a0 = 0.f, a1 = 0.f;
            uint32_t j = 0;
            for (; j + 4 <= n; j += 4) {
                uint32_t sA = lsrc[s0 + j],     sB = lsrc[s0 + j + 1];
                uint32_t sC = lsrc[s0 + j + 2], sD = lsrc[s0 + j + 3];
                uint32_t uA = hb32[(size_t)sA * 8 + f8];
                uint32_t uB = hb32[(size_t)sB * 8 + f8];
                uint32_t uC = hb32[(size_t)sC * 8 + f8];
                uint32_t uD = hb32[(size_t)sD * 8 + f8];
                a0 += (bf2f(uA & 0xFFFFu) + bf2f(uB & 0xFFFFu))
                    + (bf2f(uC & 0xFFFFu) + bf2f(uD & 0xFFFFu));
                a1 += (bf2f(uA >> 16) + bf2f(uB >> 16))
                    + (bf2f(uC >> 16) + bf2f(uD >> 16));
            }
            for (; j < n; ++j) {
                uint32_t u = hb32[(size_t)lsrc[s0 + j] * 8 + f8];
                a0 += bf2f(u & 0xFFFFu);
                a1 += bf2f(u >> 16);
            }

            const float dinv = rsqrtf((float)(n + 1u));
            const uint32_t us = hb32[(size_t)gn * 8 + f8];
            float v0 = fmaxf(fmaf(dinv, a0 + bf2f(us & 0xFFFFu), b0), 0.f);
            float v1 = fmaxf(fmaf(dinv, a1 + bf2f(us >> 16), b1), 0.f);

            float m = fmaxf(v0, v1);
            #pragma unroll
            for (int d = 1; d < 8; d <<= 1) m = fmaxf(m, __shfl_xor(m, d, 8));
            float sum = __expf(v0 - m) + __expf(v1 - m);
            #pragma unroll
            for (int d = 1; d < 8; d <<= 1) sum += __shfl_xor(sum, d, 8);
            const float ls = m + __logf(sum);

            float2 o; o.x = v0 - ls; o.y = v1 - ls;
            ((float2*)out)[(size_t)gn * 8 + f8] = o;
        }
    }
}

extern "C" void kernel_launch(void* const* d_in, const int* in_sizes, int n_in,
                              void* d_out, int out_size, void* d_ws, size_t ws_size,
                              hipStream_t stream) {
    const float* x  = (const float*)d_in[0];
    const void*  ei = d_in[1];
    const float* W  = (const float*)d_in[2];
    const float* b  = (const float*)d_in[3];
    float* out = (float*)d_out;
    int E = in_sizes[1] / 2;
    int nchunks = (E + CHUNK - 1) / CHUNK;

    char* ws = (char*)d_ws;
    uint32_t* woff   = (uint32_t*)(ws + 1024);         // 1.6 KB
    uint32_t* gpairs = (uint32_t*)(ws + (1 << 20));    // 14.42 MB
    ushort*   hb     = (ushort*)(ws + (16 << 20));     // 3.2 MB
    uint32_t* cnt    = (uint32_t*)(ws + (20 << 20));   // 400 KB

    hipMemsetAsync(woff, 0, NBUK * sizeof(uint32_t), stream);

    void* args[] = {
        (void*)&ei, (void*)&E, (void*)&nchunks,
        (void*)&woff, (void*)&gpairs,
        (void*)&x, (void*)&W,
        (void*)&hb, (void*)&cnt,
        (void*)&b, (void*)&out
    };
    hipLaunchCooperativeKernel((void*)k_mega, dim3(GRIDN), dim3(1024),
                               args, 0, stream);
}

// Round 11
// 97.516 us; speedup vs baseline: 1.8319x; 1.8319x over previous
//
#include <hip/hip_runtime.h>
#include <hip/hip_bf16.h>
#include <stdint.h>

#define N_NODES 100000
#define F_IN    512
#define HOUT    16

#define BSH   8                       // 256 nodes per bucket
#define NBUK  391                     // ceil(100000 / 256)
#define CAP   9216                    // per-bucket capacity (mean 8184, +11 sigma)
#define CHUNK 8192                    // edges per binA block
#define GEMM_BLOCKS 782               // ceil(6250 tiles / 8 waves)

typedef __attribute__((ext_vector_type(8))) short bf16x8;
typedef __attribute__((ext_vector_type(4))) float f32x4;

// f32 -> bf16 bits, round-to-nearest-even
__device__ __forceinline__ short f2bf(float f) {
    union { float f; uint32_t u; } v; v.f = f;
    uint32_t r = (v.u + 0x7FFFu + ((v.u >> 16) & 1u)) >> 16;
    return (short)r;
}
__device__ __forceinline__ float bf2f(uint32_t bits16) {
    union { uint32_t u; float f; } v; v.u = bits16 << 16;
    return v.f;
}

__device__ __forceinline__ int edge_at(const void* ei, int64_t idx, uint32_t is64) {
    if (is64) return (int)((const long long*)ei)[idx];
    return ((const int*)ei)[idx];
}

// ---- K0: zero bucket_woff + detect edge dtype (int64 vs int32) ---------
__global__ void k_init(const uint32_t* __restrict__ e_u32, uint32_t* __restrict__ flag,
                       uint32_t* __restrict__ bucket_woff) {
    const int t = threadIdx.x;
    if (t < NBUK) bucket_woff[t] = 0u;
    if (t == 0) {
        uint32_t o = 0;
        #pragma unroll
        for (int i = 1; i < 32; i += 2) o |= e_u32[i];
        flag[0] = (o == 0u) ? 1u : 0u; // 1 => int64
    }
}

// ---- K1: heterogeneous blocks: [0,nchunks) = edge binning,  ------------
// ----     [nchunks, ...) = x@W MFMA -> unscaled bf16 hb -----------------
__global__ __launch_bounds__(512) void k_fused(const void* __restrict__ ei, int E, int nchunks,
                                               const uint32_t* __restrict__ flag,
                                               uint32_t* __restrict__ bucket_woff,
                                               uint32_t* __restrict__ gpairs,
                                               const float* __restrict__ x,
                                               const float* __restrict__ W,
                                               ushort* __restrict__ hb) {
    __shared__ uint32_t h[512];        // histogram (then wave-inclusive scan)
    __shared__ uint32_t ex[512];       // exclusive scan (frozen)
    __shared__ uint32_t pcnt[512];     // placement cursors
    __shared__ uint32_t gbase[512];    // global reservation per bucket
    __shared__ uint32_t sorted[CHUNK]; // bucket-sorted packed pairs (32 KB)
    __shared__ uint16_t sbuck[CHUNK];  // bucket id per slot (16 KB)

    const int t = threadIdx.x;

    if ((int)blockIdx.x < nchunks) {
        // ---------------- binA branch ----------------
        const uint32_t is64 = flag[0];
        const int base = blockIdx.x * CHUNK;
        const int chunk_n = min(CHUNK, E - base);
        const bool evenE = ((E & 1) == 0);

        h[t] = 0;
        __syncthreads();

        uint32_t pr[16];
        uint16_t bk[16];
        #pragma unroll
        for (int k = 0; k < 8; ++k) {
            const int e0 = base + k * 1024 + 2 * t;
            uint32_t s0 = 0, s1 = 0, d0 = 0, d1 = 0;
            const bool ok0 = (e0 < E), ok1 = (e0 + 1 < E);
            if (ok1 && evenE) {
                if (is64) {
                    ulonglong2 S = *(const ulonglong2*)((const long long*)ei + e0);
                    ulonglong2 D = *(const ulonglong2*)((const long long*)ei + (int64_t)E + e0);
                    s0 = (uint32_t)S.x; s1 = (uint32_t)S.y;
                    d0 = (uint32_t)D.x; d1 = (uint32_t)D.y;
                } else {
                    uint2 S = *(const uint2*)((const int*)ei + e0);
                    uint2 D = *(const uint2*)((const int*)ei + (int64_t)E + e0);
                    s0 = S.x; s1 = S.y; d0 = D.x; d1 = D.y;
                }
            } else {
                if (ok0) { s0 = (uint32_t)edge_at(ei, e0, is64);
                           d0 = (uint32_t)edge_at(ei, (int64_t)E + e0, is64); }
                if (ok1) { s1 = (uint32_t)edge_at(ei, e0 + 1, is64);
                           d1 = (uint32_t)edge_at(ei, (int64_t)E + e0 + 1, is64); }
            }
            bk[2*k]   = 0xFFFFu;
            bk[2*k+1] = 0xFFFFu;
            if (ok0) {
                uint32_t b = d0 >> BSH;
                pr[2*k] = (s0 << BSH) | (d0 & 255u);
                bk[2*k] = (uint16_t)b;
                atomicAdd(&h[b], 1u);
            }
            if (ok1) {
                uint32_t b = d1 >> BSH;
                pr[2*k+1] = (s1 << BSH) | (d1 & 255u);
                bk[2*k+1] = (uint16_t)b;
                atomicAdd(&h[b], 1u);
            }
        }
        __syncthreads();

        // wave-shfl scan over 512 bins (8 waves x 64) — 2 barriers total
        const uint32_t hv = h[t];
        uint32_t v = hv;
        #pragma unroll
        for (int d = 1; d < 64; d <<= 1) {
            uint32_t u = __shfl_up(v, d, 64);
            if ((t & 63) >= d) v += u;
        }
        h[t] = v; // wave-inclusive
        __syncthreads();
        uint32_t wbase = 0;
        const int w = t >> 6;
        for (int w2 = 0; w2 < w; ++w2) wbase += h[w2 * 64 + 63];
        const uint32_t exv = wbase + v - hv;
        ex[t] = exv;
        pcnt[t] = exv;
        if (t < NBUK) gbase[t] = atomicAdd(&bucket_woff[t], hv);
        __syncthreads();

        #pragma unroll
        for (int k = 0; k < 16; ++k) {
            if (bk[k] != 0xFFFFu) {
                uint32_t slot = atomicAdd(&pcnt[bk[k]], 1u);
                sorted[slot] = pr[k];
                sbuck[slot] = bk[k];
            }
        }
        __syncthreads();

        #pragma unroll
        for (int k = 0; k < 16; ++k) {
            int i = k * 512 + t;
            if (i < chunk_n) {
                uint32_t b = sbuck[i];
                uint32_t pos = gbase[b] + ((uint32_t)i - ex[b]);
                gpairs[(size_t)b * CAP + pos] = sorted[i];
            }
        }
    } else {
        // ---------------- GEMM branch (unscaled bf16 out) ----------------
        const int lane = t & 63;
        const int wid  = t >> 6; // 0..7
        const int tile = ((int)blockIdx.x - nchunks) * 8 + wid;
        if (tile * 16 >= N_NODES) return;
        const int c    = lane & 15;
        const int half = lane >> 4;

        bf16x8 bfrag[16];
        #pragma unroll
        for (int s = 0; s < 16; ++s) {
            #pragma unroll
            for (int e = 0; e < 8; ++e) {
                int k = 32 * s + 8 * half + e;
                bfrag[s][e] = f2bf(W[k * HOUT + c]);
            }
        }

        const int row = tile * 16 + c;
        const float* xr = x + (int64_t)row * F_IN;
        f32x4 acc = {0.f, 0.f, 0.f, 0.f};
        #pragma unroll
        for (int s = 0; s < 16; ++s) {
            const float4 a0 = *(const float4*)(xr + 32 * s + 8 * half);
            const float4 a1 = *(const float4*)(xr + 32 * s + 8 * half + 4);
            bf16x8 af;
            af[0] = f2bf(a0.x); af[1] = f2bf(a0.y); af[2] = f2bf(a0.z); af[3] = f2bf(a0.w);
            af[4] = f2bf(a1.x); af[5] = f2bf(a1.y); af[6] = f2bf(a1.z); af[7] = f2bf(a1.w);
            acc = __builtin_amdgcn_mfma_f32_16x16x32_bf16(af, bfrag[s], acc, 0, 0, 0);
        }

        #pragma unroll
        for (int r = 0; r < 4; ++r) {
            int orow = tile * 16 + 4 * half + r;
            hb[(int64_t)orow * HOUT + c] = (ushort)f2bf(acc[r]);
        }
    }
}

// ---- K2: per-bucket histogram -> cnt; scale hb *= dinv in place --------
__global__ __launch_bounds__(256) void k_hist(const uint32_t* __restrict__ bucket_woff,
                                              const uint32_t* __restrict__ gpairs,
                                              uint32_t* __restrict__ cnt,
                                              ushort* __restrict__ hb) {
    const int b = blockIdx.x;
    const int t = threadIdx.x;
    const uint32_t count = bucket_woff[b];
    const uint32_t* gp = gpairs + (size_t)b * CAP;

    __shared__ uint32_t lc[256];
    lc[t] = 0;
    __syncthreads();
    for (uint32_t i = t; i < count; i += 256)
        atomicAdd(&lc[gp[i] & 255u], 1u);
    __syncthreads();

    const int gn = (b << BSH) + t;
    if (gn < N_NODES) {
        const uint32_t deg = lc[t];
        cnt[gn] = deg;
        const float dinv = rsqrtf((float)(deg + 1u));
        ushort* row = hb + (size_t)gn * HOUT;
        ulonglong4 rv = *(const ulonglong4*)row;
        ushort u[16];
        *(ulonglong4*)u = rv;
        #pragma unroll
        for (int q = 0; q < 16; ++q)
            u[q] = (ushort)f2bf(bf2f(u[q]) * dinv);
        *(ulonglong4*)row = *(const ulonglong4*)u;
    }
}

// ---- K3: fused per-bucket sort(to LDS) + gather-aggregate + epilogue ----
// 1024 threads, 16-lane feature groups (the best-measured R6 layout).
__global__ __launch_bounds__(1024) void k_sortagg(const uint32_t* __restrict__ bucket_woff,
                                                  const uint32_t* __restrict__ gpairs,
                                                  const uint32_t* __restrict__ cnt,
                                                  const ushort* __restrict__ hb,
                                                  const float* __restrict__ bias,
                                                  float* __restrict__ out) {
    const int bk = blockIdx.x;
    const int t = threadIdx.x;
    const uint32_t count = bucket_woff[bk];
    const uint32_t* gp = gpairs + (size_t)bk * CAP;

    __shared__ uint32_t lc[256];   // per-node degree
    __shared__ uint32_t st[256];   // run start (frozen)
    __shared__ uint32_t cur[256];  // placement cursor
    __shared__ uint32_t lsrc[CAP]; // srcs sorted by dst-local (36 KB)

    if (t < 256) {
        int gn = (bk << BSH) + t;
        lc[t] = (gn < N_NODES) ? cnt[gn] : 0u;
    }
    __syncthreads();
    if (t < 256) {
        const uint32_t hv = lc[t];
        uint32_t v = hv;
        #pragma unroll
        for (int d = 1; d < 64; d <<= 1) {
            uint32_t u = __shfl_up(v, d, 64);
            if ((t & 63) >= d) v += u;
        }
        cur[t] = v;   // wave-inclusive (temp)
    }
    __syncthreads();
    if (t < 256) {
        uint32_t wb = 0;
        const int w = t >> 6;
        for (int w2 = 0; w2 < w; ++w2) wb += cur[w2 * 64 + 63];
        st[t] = wb + cur[t] - lc[t];
    }
    __syncthreads();
    if (t < 256) cur[t] = st[t];
    __syncthreads();

    for (uint32_t i = t; i < count; i += 1024) {
        uint32_t p = gp[i];
        uint32_t pos = atomicAdd(&cur[p & 255u], 1u);
        lsrc[pos] = p >> BSH;
    }
    __syncthreads();

    const int f = t & 15;
    const int g = t >> 4; // 0..63
    const float bf = bias[f];

    #pragma unroll
    for (int i = 0; i < 4; ++i) {
        int dl = g + 64 * i;
        int gn = (bk << BSH) + dl;
        if (gn >= N_NODES) break;
        const uint32_t s0 = st[dl];
        const uint32_t n  = lc[dl];

        float acc = 0.f;
        uint32_t j = 0;
        for (; j + 4 <= n; j += 4) {
            uint32_t a = lsrc[s0 + j], b2 = lsrc[s0 + j + 1];
            uint32_t c2 = lsrc[s0 + j + 2], d2 = lsrc[s0 + j + 3];
            float v0 = bf2f(hb[(size_t)a  * HOUT + f]);
            float v1 = bf2f(hb[(size_t)b2 * HOUT + f]);
            float v2 = bf2f(hb[(size_t)c2 * HOUT + f]);
            float v3 = bf2f(hb[(size_t)d2 * HOUT + f]);
            acc += (v0 + v1) + (v2 + v3);
        }
        for (; j < n; ++j)
            acc += bf2f(hb[(size_t)lsrc[s0 + j] * HOUT + f]);

        const float dinv = rsqrtf((float)(n + 1u));
        const float self = bf2f(hb[(size_t)gn * HOUT + f]);
        float v = fmaxf(fmaf(dinv, acc + self, bf), 0.f);

        float m = v;
        #pragma unroll
        for (int d = 1; d < 16; d <<= 1) m = fmaxf(m, __shfl_xor(m, d));
        float ex = __expf(v - m);
        float sum = ex;
        #pragma unroll
        for (int d = 1; d < 16; d <<= 1) sum += __shfl_xor(sum, d);
        out[(size_t)gn * HOUT + f] = v - (m + __logf(sum));
    }
}

extern "C" void kernel_launch(void* const* d_in, const int* in_sizes, int n_in,
                              void* d_out, int out_size, void* d_ws, size_t ws_size,
                              hipStream_t stream) {
    const float* x  = (const float*)d_in[0];
    const void*  ei = d_in[1];
    const float* W  = (const float*)d_in[2];
    const float* b  = (const float*)d_in[3];
    float* out = (float*)d_out;
    const int E = in_sizes[1] / 2;
    const int nchunks = (E + CHUNK - 1) / CHUNK;

    char* ws = (char*)d_ws;
    uint32_t* flag        = (uint32_t*)ws;                  // 4 B
    uint32_t* bucket_woff = (uint32_t*)(ws + 1024);         // 1.6 KB
    uint32_t* gpairs      = (uint32_t*)(ws + (1 << 20));    // 14.42 MB
    ushort*   hb          = (ushort*)(ws + (16 << 20));     // 3.2 MB
    uint32_t* cnt         = (uint32_t*)(ws + (20 << 20));   // 400 KB

    k_init<<<1, 512, 0, stream>>>((const uint32_t*)ei, flag, bucket_woff);
    k_fused<<<nchunks + GEMM_BLOCKS, 512, 0, stream>>>(ei, E, nchunks, flag,
                                                       bucket_woff, gpairs, x, W, hb);
    k_hist<<<NBUK, 256, 0, stream>>>(bucket_woff, gpairs, cnt, hb);
    k_sortagg<<<NBUK, 1024, 0, stream>>>(bucket_woff, gpairs, cnt, hb, b, out);
}